// Round 5
// baseline (2008.671 us; speedup 1.0000x reference)
//
#include <hip/hip_runtime.h>
#include <hip/hip_bf16.h>
#include <stdint.h>
#include <stddef.h>

#define NL 8
#define NH 12
#define CC 576
#define VV 16389
#define TT 1024
#define HD 48
#define BT 2048
#define C3 1728
#define C2 1152

typedef __attribute__((ext_vector_type(4))) float f32x4;
typedef __attribute__((ext_vector_type(8))) __bf16 bf16x8;
typedef __attribute__((ext_vector_type(8))) unsigned short u16x8;

static __device__ __forceinline__ unsigned short f2bf(float f) {
  __hip_bfloat16 h = __float2bfloat16(f);
  return __builtin_bit_cast(unsigned short, h);
}
static __device__ __forceinline__ float bf2f(unsigned short u) {
  __hip_bfloat16 h = __builtin_bit_cast(__hip_bfloat16, u);
  return __bfloat162float(h);
}
static __device__ __forceinline__ float gelu_tanh(float g) {
  float t = tanhf(0.7978845608028654f * (g + 0.044715f * g * g * g));
  return 0.5f * g * (1.f + t);
}

// ---------------- fp32 -> bf16 convert (weights) ----------------
__global__ void cvt_kernel(const float* __restrict__ in, unsigned short* __restrict__ out, int n4) {
  int i = blockIdx.x * blockDim.x + threadIdx.x;
  int stride = gridDim.x * blockDim.x;
  for (; i < n4; i += stride) {
    float4 v = reinterpret_cast<const float4*>(in)[i];
    ushort4 o;
    o.x = f2bf(v.x); o.y = f2bf(v.y); o.z = f2bf(v.z); o.w = f2bf(v.w);
    reinterpret_cast<ushort4*>(out)[i] = o;
  }
}

// gate/up row-interleave convert: out row 2j = Wg[j], row 2j+1 = Wu[j], per layer
__global__ void cvt_gu_kernel(const float* __restrict__ g, const float* __restrict__ u,
                              unsigned short* __restrict__ out, int n4) {
  int i = blockIdx.x * blockDim.x + threadIdx.x;
  int stride = gridDim.x * blockDim.x;
  const int per_l = C2 * (CC / 4);   // float4s per layer per matrix
  for (; i < n4; i += stride) {
    int l = i / per_l, rem = i - l * per_l;
    int j = rem / (CC / 4), c4 = rem - j * (CC / 4);
    float4 gv = reinterpret_cast<const float4*>(g)[i];
    float4 uv = reinterpret_cast<const float4*>(u)[i];
    ushort4 go, uo;
    go.x = f2bf(gv.x); go.y = f2bf(gv.y); go.z = f2bf(gv.z); go.w = f2bf(gv.w);
    uo.x = f2bf(uv.x); uo.y = f2bf(uv.y); uo.z = f2bf(uv.z); uo.w = f2bf(uv.w);
    size_t dst = ((size_t)l * 2 * C2 + 2 * j) * CC + c4 * 4;
    *reinterpret_cast<ushort4*>(out + dst) = go;
    *reinterpret_cast<ushort4*>(out + dst + CC) = uo;
  }
}

// ---------------- embedding gather ----------------
__global__ void embed_kernel(const int* __restrict__ idx, const float* __restrict__ wte,
                             float* __restrict__ x, float* __restrict__ x0,
                             unsigned short* __restrict__ xbf) {
  int t = blockIdx.x;
  int tok = idx[t];
  const float* src = wte + (size_t)tok * CC;
  size_t base = (size_t)t * CC;
  for (int c = threadIdx.x; c < CC; c += blockDim.x) {
    float v = src[c];
    x[base + c] = v;
    x0[base + c] = v;
    xbf[base + c] = f2bf(v);
  }
}

// ---------------- bf16 MFMA GEMM with fused-LN A-staging ----------------
// C[2048,N] (+)= A[2048,K] * W[N,K]^T
// LNA: 0 = A is bf16 (Xb). 1 = A = LN(lam0*Xf+lam1*X0)*w+b, n0==0 blocks write mix to xmixout.
//      2 = A = LN(Xf)*w+b.
// EPI: 0 fp32 store | 1 fp32 += | 2 30*tanh(v/30) | 3 bf16 store
//      4 qkv split: cols<1152 -> qkb, cols>=1152 -> vmix=bf16(0.5v+0.5*v1b)
//      5 geglu interleaved -> bf16 stride N/2
template<int EPI, int BM, int BN, int LNA>
__global__ __launch_bounds__(256) void gemm_bt(
    const unsigned short* __restrict__ Xb, const float* __restrict__ Xf,
    const float* __restrict__ X0, const float* __restrict__ lam,
    const float* __restrict__ lnw, const float* __restrict__ lnb,
    float* __restrict__ xmixout,
    const unsigned short* __restrict__ W,
    float* __restrict__ Cf, unsigned short* __restrict__ Cb,
    unsigned short* __restrict__ Cb2, const unsigned short* __restrict__ v1b,
    int N, int K) {
  constexpr int NMB = BT / BM;       // m-blocks
  constexpr int PA = BM / 32;        // A staging chunks
  constexpr int PB = BN / 32;        // B staging chunks
  constexpr int MI = BM / 32;        // per-wave m frags
  constexpr int NI = BN / 32;        // per-wave n frags
  __shared__ unsigned short As[BM * 64];
  __shared__ unsigned short Bs[BN * 64];
  __shared__ float MuS[(LNA > 0) ? BM : 1];
  __shared__ float RsS[(LNA > 0) ? BM : 1];
  __shared__ float WbS[(LNA > 0) ? CC : 1];
  __shared__ float BbS[(LNA > 0) ? CC : 1];
  const int tid = threadIdx.x;
  const int lane = tid & 63;
  const int wv = tid >> 6;
  const int wr = wv >> 1, wc = wv & 1;
  const int nwg = gridDim.x;
  const int bid = blockIdx.x;
  const int swz = (bid & 7) * (nwg >> 3) + (bid >> 3);   // bijective: nwg%8==0
  const int m0 = (swz % NMB) * BM;
  const int n0 = (swz / NMB) * BN;
  const int l15 = lane & 15, g = lane >> 4;
  const int trow = tid >> 3;         // 0..31
  const int tcb = (tid & 7) << 4;    // byte col in staging row

  float lam0 = 1.f, lam1 = 0.f;
  if (LNA == 1) { lam0 = lam[0]; lam1 = lam[1]; }

  // ---- fused-LN preamble: row stats for this m-panel ----
  if (LNA > 0) {
    for (int c = tid; c < CC; c += 256) { WbS[c] = lnw[c]; BbS[c] = lnb[c]; }
    for (int rr = 0; rr < BM / 4; ++rr) {
      int r = wv * (BM / 4) + rr;
      size_t grow = (size_t)(m0 + r) * CC;
      float e[9];
      float s = 0.f;
#pragma unroll
      for (int j = 0; j < 9; ++j) {
        int c = lane + 64 * j;
        float v = Xf[grow + c];
        if (LNA == 1) v = lam0 * v + lam1 * X0[grow + c];
        e[j] = v; s += v;
      }
#pragma unroll
      for (int mm = 1; mm < 64; mm <<= 1) s += __shfl_xor(s, mm, 64);
      float mu = s * (1.f / 576.f);
      float var = 0.f;
#pragma unroll
      for (int j = 0; j < 9; ++j) { float d = e[j] - mu; var += d * d; }
#pragma unroll
      for (int mm = 1; mm < 64; mm <<= 1) var += __shfl_xor(var, mm, 64);
      float rstd = 1.f / sqrtf(var * (1.f / 576.f) + 1e-5f);
      if (lane == 0) { MuS[r] = mu; RsS[r] = rstd; }
      if (LNA == 1 && n0 == 0) {
#pragma unroll
        for (int j = 0; j < 9; ++j) xmixout[grow + lane + 64 * j] = e[j];
      }
    }
    __syncthreads();
  }

  // A-chunk loader: returns bf16x8-packed A for chunk p at k-offset k
  auto ldA = [&](int p, int k) -> u16x8 {
    int r = p * 32 + trow;
    int c0 = (tid & 7) * 8;
    if (LNA == 0) {
      return *reinterpret_cast<const u16x8*>(Xb + (size_t)(m0 + r) * K + c0 + k);
    } else {
      size_t base = (size_t)(m0 + r) * CC + c0 + k;
      float4 a0 = *reinterpret_cast<const float4*>(Xf + base);
      float4 a1 = *reinterpret_cast<const float4*>(Xf + base + 4);
      float ev[8] = {a0.x, a0.y, a0.z, a0.w, a1.x, a1.y, a1.z, a1.w};
      if (LNA == 1) {
        float4 b0 = *reinterpret_cast<const float4*>(X0 + base);
        float4 b1 = *reinterpret_cast<const float4*>(X0 + base + 4);
        float bv[8] = {b0.x, b0.y, b0.z, b0.w, b1.x, b1.y, b1.z, b1.w};
#pragma unroll
        for (int i = 0; i < 8; ++i) ev[i] = lam0 * ev[i] + lam1 * bv[i];
      }
      float mu = MuS[r], rs = RsS[r];
      union { u16x8 v; unsigned short u[8]; } o;
#pragma unroll
      for (int i = 0; i < 8; ++i)
        o.u[i] = f2bf((ev[i] - mu) * rs * WbS[c0 + k + i] + BbS[c0 + k + i]);
      return o.v;
    }
  };

  const unsigned short* wrow[PB];
  int aoff[PA], boff[PB];
#pragma unroll
  for (int p = 0; p < PA; ++p) {
    int r = p * 32 + trow;
    aoff[p] = r * 128 + (tcb ^ ((trow & 7) << 4));   // T2 XOR swizzle
  }
#pragma unroll
  for (int p = 0; p < PB; ++p) {
    int r = p * 32 + trow;
    int rn = n0 + r; if (rn > N - 1) rn = N - 1;     // clamp OOB N rows
    wrow[p] = W + (size_t)rn * K + (tcb >> 1);
    boff[p] = r * 128 + (tcb ^ ((trow & 7) << 4));
  }
  const int rdswz = (l15 & 7) << 4;

  f32x4 acc[MI][NI];
  const f32x4 fz = {0.f, 0.f, 0.f, 0.f};
#pragma unroll
  for (int i = 0; i < MI; ++i)
#pragma unroll
    for (int j = 0; j < NI; ++j) acc[i][j] = fz;

  u16x8 stg[PA + PB];
#pragma unroll
  for (int p = 0; p < PA; ++p) stg[p] = ldA(p, 0);
#pragma unroll
  for (int p = 0; p < PB; ++p) stg[PA + p] = *reinterpret_cast<const u16x8*>(wrow[p]);

  for (int k0 = 0; k0 < K; k0 += 64) {
    __syncthreads();
#pragma unroll
    for (int p = 0; p < PA; ++p)
      *reinterpret_cast<u16x8*>(reinterpret_cast<char*>(As) + aoff[p]) = stg[p];
#pragma unroll
    for (int p = 0; p < PB; ++p)
      *reinterpret_cast<u16x8*>(reinterpret_cast<char*>(Bs) + boff[p]) = stg[PA + p];
    __syncthreads();
    if (k0 + 64 < K) {
#pragma unroll
      for (int p = 0; p < PA; ++p) stg[p] = ldA(p, k0 + 64);
#pragma unroll
      for (int p = 0; p < PB; ++p)
        stg[PA + p] = *reinterpret_cast<const u16x8*>(wrow[p] + k0 + 64);
    }
#pragma unroll
    for (int kk = 0; kk < 2; ++kk) {
      const int kbyte = kk * 64 + g * 16;
      bf16x8 a[MI], bb[NI];
#pragma unroll
      for (int mi = 0; mi < MI; ++mi) {
        int ar = wr * (BM / 2) + mi * 16 + l15;
        a[mi] = *reinterpret_cast<const bf16x8*>(
            reinterpret_cast<const char*>(As) + ar * 128 + (kbyte ^ rdswz));
      }
#pragma unroll
      for (int ni = 0; ni < NI; ++ni) {
        int br = wc * (BN / 2) + ni * 16 + l15;
        bb[ni] = *reinterpret_cast<const bf16x8*>(
            reinterpret_cast<const char*>(Bs) + br * 128 + (kbyte ^ rdswz));
      }
#pragma unroll
      for (int mi = 0; mi < MI; ++mi)
#pragma unroll
        for (int ni = 0; ni < NI; ++ni)
          acc[mi][ni] = __builtin_amdgcn_mfma_f32_16x16x32_bf16(a[mi], bb[ni], acc[mi][ni], 0, 0, 0);
    }
  }
#pragma unroll
  for (int mi = 0; mi < MI; ++mi) {
#pragma unroll
    for (int ni = 0; ni < NI; ++ni) {
      int gn = n0 + wc * (BN / 2) + ni * 16 + l15;
      int gm = m0 + wr * (BM / 2) + mi * 16 + g * 4;
#pragma unroll
      for (int r = 0; r < 4; ++r) {
        float v = acc[mi][ni][r];
        size_t row = (size_t)(gm + r);
        if (EPI == 5) {
          float partner = __shfl_xor(v, 1, 64);
          if ((l15 & 1) == 0 && gn < N)
            Cb[row * (N / 2) + (gn >> 1)] = f2bf(gelu_tanh(v) * partner);
        } else if (gn < N) {
          if (EPI == 0) Cf[row * N + gn] = v;
          else if (EPI == 1) Cf[row * N + gn] += v;
          else if (EPI == 2) Cf[row * N + gn] = 30.f * tanhf(v * (1.f / 30.f));
          else if (EPI == 3) Cb[row * N + gn] = f2bf(v);
          else if (EPI == 4) {
            if (gn < C2) Cb[row * C2 + gn] = f2bf(v);                       // q,k
            else Cb2[row * CC + (gn - C2)] = f2bf(0.5f * v + 0.5f * bf2f(v1b[row * CC + (gn - C2)]));
          }
        }
      }
    }
  }
}

// ---------------- flash attention (causal; ALiBi dead on causal region) ----------------
__global__ __launch_bounds__(256) void attn_kernel(
    const unsigned short* __restrict__ qkb, const unsigned short* __restrict__ vmix,
    unsigned short* __restrict__ ybf) {
  __shared__ unsigned short Kl[64 * 56];     // K tile, row pad 56
  __shared__ unsigned short Vt[48 * 72];     // V tile transposed [d][key], row pad 72
  __shared__ unsigned short Pl[4][16 * 72];  // per-wave P buffer [q][key]
  const int bid = blockIdx.x;                // 384 = 8*48
  const int swz = (bid & 7) * 48 + (bid >> 3);
  const int qb = swz & 15, bh = swz >> 4;
  const int b = bh / NH, h = bh % NH;
  const int tid = threadIdx.x, lane = tid & 63, wv = tid >> 6;
  const int l15 = lane & 15, g = lane >> 4;
  const int rb = b * TT;
  const int q0 = qb * 64 + wv * 16;
  const float scale = 0.14433756729740643f;  // 1/sqrt(48)

  bf16x8 qa[2];
  {
    const unsigned short* qp = qkb + (size_t)(rb + q0 + l15) * C2 + h * HD;
    qa[0] = *reinterpret_cast<const bf16x8*>(qp + 8 * g);
    if (g < 2) qa[1] = *reinterpret_cast<const bf16x8*>(qp + 32 + 8 * g);
    else { u16x8 z = {0,0,0,0,0,0,0,0}; qa[1] = __builtin_bit_cast(bf16x8, z); }
  }

  float mrow[4], lrow[4];
  f32x4 o[3];
  const f32x4 fz = {0.f, 0.f, 0.f, 0.f};
#pragma unroll
  for (int r = 0; r < 4; ++r) { mrow[r] = -1e30f; lrow[r] = 0.f; }
  o[0] = fz; o[1] = fz; o[2] = fz;

  for (int kb = 0; kb <= qb; ++kb) {
    __syncthreads();
#pragma unroll
    for (int jj = 0; jj < 3; ++jj) {
      int fi = tid + 256 * jj;                 // 0..767
      int r = fi / 12, dq = (fi % 12) * 4;
      *reinterpret_cast<ushort4*>(&Kl[r * 56 + dq]) =
          *reinterpret_cast<const ushort4*>(qkb + (size_t)(rb + kb * 64 + r) * C2 + CC + h * HD + dq);
    }
#pragma unroll
    for (int jj = 0; jj < 12; ++jj) {
      int e = tid + 256 * jj;                  // 0..3071
      int r = e / 48, d = e - r * 48;
      Vt[d * 72 + r] = vmix[(size_t)(rb + kb * 64 + r) * CC + h * HD + d];
    }
    __syncthreads();

    f32x4 s[4];
    s[0] = fz; s[1] = fz; s[2] = fz; s[3] = fz;
#pragma unroll
    for (int c = 0; c < 2; ++c) {
#pragma unroll
      for (int t4 = 0; t4 < 4; ++t4) {
        bf16x8 kf;
        if (c == 1 && g >= 2) {
          u16x8 z = {0,0,0,0,0,0,0,0};
          kf = __builtin_bit_cast(bf16x8, z);
        } else {
          kf = *reinterpret_cast<const bf16x8*>(&Kl[(t4 * 16 + l15) * 56 + c * 32 + 8 * g]);
        }
        s[t4] = __builtin_amdgcn_mfma_f32_16x16x32_bf16(qa[c], kf, s[t4], 0, 0, 0);
      }
    }
#pragma unroll
    for (int t4 = 0; t4 < 4; ++t4) s[t4] *= scale;
    if (kb == qb) {
#pragma unroll
      for (int t4 = 0; t4 < 4; ++t4) {
        int key = kb * 64 + t4 * 16 + l15;
#pragma unroll
        for (int r = 0; r < 4; ++r)
          if (key > q0 + g * 4 + r) s[t4][r] = -1e30f;
      }
    }
    float pv[4][4];
#pragma unroll
    for (int r = 0; r < 4; ++r) {
      float tm = fmaxf(fmaxf(s[0][r], s[1][r]), fmaxf(s[2][r], s[3][r]));
#pragma unroll
      for (int mm = 1; mm < 16; mm <<= 1) tm = fmaxf(tm, __shfl_xor(tm, mm, 64));
      float mnew = fmaxf(mrow[r], tm);
      float cf = __expf(mrow[r] - mnew);
      lrow[r] *= cf;
      o[0][r] *= cf; o[1][r] *= cf; o[2][r] *= cf;
      mrow[r] = mnew;
      float rs = 0.f;
#pragma unroll
      for (int t4 = 0; t4 < 4; ++t4) {
        float pe = __expf(s[t4][r] - mnew);
        pv[t4][r] = pe; rs += pe;
      }
#pragma unroll
      for (int mm = 1; mm < 16; mm <<= 1) rs += __shfl_xor(rs, mm, 64);
      lrow[r] += rs;
    }
#pragma unroll
    for (int t4 = 0; t4 < 4; ++t4)
#pragma unroll
      for (int r = 0; r < 4; ++r)
        Pl[wv][(g * 4 + r) * 72 + t4 * 16 + l15] = f2bf(pv[t4][r]);
#pragma unroll
    for (int c = 0; c < 2; ++c) {
      bf16x8 pa = *reinterpret_cast<const bf16x8*>(&Pl[wv][l15 * 72 + c * 32 + 8 * g]);
#pragma unroll
      for (int dt = 0; dt < 3; ++dt) {
        bf16x8 vb = *reinterpret_cast<const bf16x8*>(&Vt[(dt * 16 + l15) * 72 + c * 32 + 8 * g]);
        o[dt] = __builtin_amdgcn_mfma_f32_16x16x32_bf16(pa, vb, o[dt], 0, 0, 0);
      }
    }
  }
#pragma unroll
  for (int r = 0; r < 4; ++r) {
    float inv = 1.f / lrow[r];
    int tr = q0 + g * 4 + r;
#pragma unroll
    for (int dt = 0; dt < 3; ++dt)
      ybf[(size_t)(rb + tr) * CC + h * HD + dt * 16 + l15] = f2bf(o[dt][r] * inv);
  }
}

// ---------------- launcher ----------------
extern "C" void kernel_launch(void* const* d_in, const int* in_sizes, int n_in,
                              void* d_out, int out_size, void* d_ws, size_t ws_size,
                              hipStream_t stream) {
  (void)in_sizes; (void)n_in; (void)out_size; (void)ws_size;
  const int*   idx  = (const int*)d_in[0];
  const float* wte  = (const float*)d_in[1];
  const float* Wqkv = (const float*)d_in[2];
  const float* Wo   = (const float*)d_in[3];
  const float* ln1w = (const float*)d_in[4];
  const float* ln1b = (const float*)d_in[5];
  const float* ln2w = (const float*)d_in[6];
  const float* ln2b = (const float*)d_in[7];
  const float* lam  = (const float*)d_in[8];
  const float* Wg   = (const float*)d_in[9];
  const float* Wu   = (const float*)d_in[10];
  const float* Wd   = (const float*)d_in[11];
  const float* lnfw = (const float*)d_in[12];
  const float* lnfb = (const float*)d_in[13];
  float* out = (float*)d_out;

  char* ws = (char*)d_ws;
  size_t off = 0;
  auto alloc = [&](size_t bytes) -> void* {
    void* p = ws + off;
    off = (off + bytes + 255) & ~(size_t)255;
    return p;
  };
  unsigned short* wqkv_b = (unsigned short*)alloc((size_t)NL * C3 * CC * 2);
  unsigned short* wo_b   = (unsigned short*)alloc((size_t)NL * CC * CC * 2);
  unsigned short* wgu_b  = (unsigned short*)alloc((size_t)NL * 2 * C2 * CC * 2);
  unsigned short* wd_b   = (unsigned short*)alloc((size_t)NL * CC * C2 * 2);
  unsigned short* wte_b  = (unsigned short*)alloc((size_t)VV * CC * 2);
  float* xe  = (float*)alloc((size_t)BT * CC * 4);
  float* x0  = (float*)alloc((size_t)BT * CC * 4);
  float* xb1 = (float*)alloc((size_t)BT * CC * 4);
  float* xb2 = (float*)alloc((size_t)BT * CC * 4);
  unsigned short* hb    = (unsigned short*)alloc((size_t)BT * CC * 2);
  unsigned short* qkb   = (unsigned short*)alloc((size_t)BT * C2 * 2);
  unsigned short* v1b   = (unsigned short*)alloc((size_t)BT * CC * 2);
  unsigned short* vmixb = (unsigned short*)alloc((size_t)BT * CC * 2);
  unsigned short* yb    = (unsigned short*)alloc((size_t)BT * CC * 2);
  unsigned short* gub   = (unsigned short*)alloc((size_t)BT * C2 * 2);

  auto cvt = [&](const float* in, unsigned short* o, size_t n) {
    cvt_kernel<<<dim3(2048), 256, 0, stream>>>(in, o, (int)(n / 4));
  };
  cvt(Wqkv, wqkv_b, (size_t)NL * C3 * CC);
  cvt(Wo,   wo_b,   (size_t)NL * CC * CC);
  cvt(Wd,   wd_b,   (size_t)NL * CC * C2);
  cvt(wte,  wte_b,  (size_t)VV * CC);
  cvt_gu_kernel<<<dim3(2048), 256, 0, stream>>>(Wg, Wu, wgu_b, NL * C2 * (CC / 4));

  embed_kernel<<<dim3(BT), 256, 0, stream>>>(idx, wte, xe, x0, hb);

  auto nb = [](int N, int BN) { return (N + BN - 1) / BN; };
  // v1 = raw-embed @ W_qkv[0] v-chunk^T  -> bf16
  gemm_bt<3, 64, 64, 0><<<dim3(32 * nb(CC, 64)), 256, 0, stream>>>(
      hb, nullptr, nullptr, nullptr, nullptr, nullptr, nullptr,
      wqkv_b + (size_t)C2 * CC, nullptr, v1b, nullptr, nullptr, CC, CC);

  float* cur = xe;
  float* nxt = xb1;
  for (int l = 0; l < NL; ++l) {
    // qkv GEMM with fused lambda-mix + LN1 (writes mix to nxt via n0==0 blocks)
    gemm_bt<4, 128, 128, 1><<<dim3(16 * nb(C3, 128)), 256, 0, stream>>>(
        nullptr, cur, x0, lam + 2 * l, ln1w + l * CC, ln1b + l * CC, nxt,
        wqkv_b + (size_t)l * C3 * CC, nullptr, qkb, vmixb, v1b, C3, CC);
    attn_kernel<<<dim3(16 * 24), 256, 0, stream>>>(qkb, vmixb, yb);
    gemm_bt<1, 64, 64, 0><<<dim3(32 * nb(CC, 64)), 256, 0, stream>>>(
        yb, nullptr, nullptr, nullptr, nullptr, nullptr, nullptr,
        wo_b + (size_t)l * CC * CC, nxt, nullptr, nullptr, nullptr, CC, CC);
    // gate/up GEMM with fused LN2, GEGLU epilogue
    gemm_bt<5, 128, 128, 2><<<dim3(16 * nb(2 * C2, 128)), 256, 0, stream>>>(
        nullptr, nxt, nullptr, nullptr, ln2w + l * CC, ln2b + l * CC, nullptr,
        wgu_b + (size_t)l * 2 * C2 * CC, nullptr, gub, nullptr, nullptr, 2 * C2, CC);
    gemm_bt<1, 64, 64, 0><<<dim3(32 * nb(CC, 64)), 256, 0, stream>>>(
        gub, nullptr, nullptr, nullptr, nullptr, nullptr, nullptr,
        wd_b + (size_t)l * CC * C2, nxt, nullptr, nullptr, nullptr, CC, C2);
    cur = nxt;
    nxt = (cur == xb1) ? xb2 : xb1;
  }

  // lm_head with fused final LN + logit clamp
  gemm_bt<2, 128, 128, 2><<<dim3(16 * nb(VV, 128)), 256, 0, stream>>>(
      nullptr, cur, nullptr, nullptr, lnfw, lnfb, nullptr,
      wte_b, out, nullptr, nullptr, nullptr, VV, CC);
}

// Round 7
// 1145.225 us; speedup vs baseline: 1.7540x; 1.7540x over previous
//
#include <hip/hip_runtime.h>
#include <hip/hip_bf16.h>
#include <stdint.h>
#include <stddef.h>

#define NL 8
#define NH 12
#define CC 576
#define VV 16389
#define TT 1024
#define HD 48
#define BT 2048
#define C3 1728
#define C2 1152

typedef __attribute__((ext_vector_type(4))) float f32x4;
typedef __attribute__((ext_vector_type(8))) __bf16 bf16x8;
typedef __attribute__((ext_vector_type(8))) unsigned short u16x8;

static __device__ __forceinline__ unsigned short f2bf(float f) {
  __hip_bfloat16 h = __float2bfloat16(f);
  return __builtin_bit_cast(unsigned short, h);
}
static __device__ __forceinline__ float bf2f(unsigned short u) {
  __hip_bfloat16 h = __builtin_bit_cast(__hip_bfloat16, u);
  return __bfloat162float(h);
}
static __device__ __forceinline__ float gelu_tanh(float g) {
  float t = tanhf(0.7978845608028654f * (g + 0.044715f * g * g * g));
  return 0.5f * g * (1.f + t);
}

// ---------------- fp32 -> bf16 convert (weights) ----------------
__global__ void cvt_kernel(const float* __restrict__ in, unsigned short* __restrict__ out, int n4) {
  int i = blockIdx.x * blockDim.x + threadIdx.x;
  int stride = gridDim.x * blockDim.x;
  for (; i < n4; i += stride) {
    float4 v = reinterpret_cast<const float4*>(in)[i];
    ushort4 o;
    o.x = f2bf(v.x); o.y = f2bf(v.y); o.z = f2bf(v.z); o.w = f2bf(v.w);
    reinterpret_cast<ushort4*>(out)[i] = o;
  }
}

// gate/up row-interleave convert: out row 2j = Wg[j], row 2j+1 = Wu[j], per layer
__global__ void cvt_gu_kernel(const float* __restrict__ g, const float* __restrict__ u,
                              unsigned short* __restrict__ out, int n4) {
  int i = blockIdx.x * blockDim.x + threadIdx.x;
  int stride = gridDim.x * blockDim.x;
  const int per_l = C2 * (CC / 4);   // float4s per layer per matrix
  for (; i < n4; i += stride) {
    int l = i / per_l, rem = i - l * per_l;
    int j = rem / (CC / 4), c4 = rem - j * (CC / 4);
    float4 gv = reinterpret_cast<const float4*>(g)[i];
    float4 uv = reinterpret_cast<const float4*>(u)[i];
    ushort4 go, uo;
    go.x = f2bf(gv.x); go.y = f2bf(gv.y); go.z = f2bf(gv.z); go.w = f2bf(gv.w);
    uo.x = f2bf(uv.x); uo.y = f2bf(uv.y); uo.z = f2bf(uv.z); uo.w = f2bf(uv.w);
    size_t dst = ((size_t)l * 2 * C2 + 2 * j) * CC + c4 * 4;
    *reinterpret_cast<ushort4*>(out + dst) = go;
    *reinterpret_cast<ushort4*>(out + dst + CC) = uo;
  }
}

// ---------------- embedding gather ----------------
__global__ void embed_kernel(const int* __restrict__ idx, const float* __restrict__ wte,
                             float* __restrict__ x, float* __restrict__ x0,
                             unsigned short* __restrict__ xbf) {
  int t = blockIdx.x;
  int tok = idx[t];
  const float* src = wte + (size_t)tok * CC;
  size_t base = (size_t)t * CC;
  for (int c = threadIdx.x; c < CC; c += blockDim.x) {
    float v = src[c];
    x[base + c] = v;
    x0[base + c] = v;
    xbf[base + c] = f2bf(v);
  }
}

// ---------------- layernorm (+ optional lambda mix written back to x) ----------------
template<int MIX>
__global__ __launch_bounds__(256) void ln_kernel(
    const float* __restrict__ xin, const float* __restrict__ x0,
    const float* __restrict__ lam, const float* __restrict__ w,
    const float* __restrict__ b, float* __restrict__ xmix,
    unsigned short* __restrict__ hbf) {
  int row = blockIdx.x * 4 + (threadIdx.x >> 6);
  int lane = threadIdx.x & 63;
  size_t base = (size_t)row * CC;
  float lam0 = 1.f, lam1 = 0.f;
  if (MIX) { lam0 = lam[0]; lam1 = lam[1]; }
  float e[9];
  float s = 0.f;
#pragma unroll
  for (int j = 0; j < 9; ++j) {
    int c = lane + 64 * j;
    float v = xin[base + c];
    if (MIX) v = lam0 * v + lam1 * x0[base + c];
    e[j] = v; s += v;
  }
#pragma unroll
  for (int mm = 1; mm < 64; mm <<= 1) s += __shfl_xor(s, mm, 64);
  float mu = s * (1.f / 576.f);
  float var = 0.f;
#pragma unroll
  for (int j = 0; j < 9; ++j) { float d = e[j] - mu; var += d * d; }
#pragma unroll
  for (int mm = 1; mm < 64; mm <<= 1) var += __shfl_xor(var, mm, 64);
  float rstd = 1.f / sqrtf(var * (1.f / 576.f) + 1e-5f);
#pragma unroll
  for (int j = 0; j < 9; ++j) {
    int c = lane + 64 * j;
    if (MIX) xmix[base + c] = e[j];
    hbf[base + c] = f2bf((e[j] - mu) * rstd * w[c] + b[c]);
  }
}

// ---------------- bf16 MFMA GEMM: C[2048,N] (+)= X[2048,K] * W[N,K]^T ----------------
// 1D grid, m-fastest + bijective XCD swizzle (requires gridDim.x % 8 == 0).
// EPI: 0 fp32 store | 1 fp32 += | 2 30*tanh(v/30) fp32 | 3 bf16 store
//      4 qkv split: cols<1152 -> qkb; cols>=1152 -> vmix=bf16(0.5v+0.5*v1b)
//      5 geglu interleaved -> bf16, out stride N/2
template<int EPI, int BM, int BN>
__global__ __launch_bounds__(256) void gemm_bt(
    const unsigned short* __restrict__ X, const unsigned short* __restrict__ W,
    float* __restrict__ Cf, unsigned short* __restrict__ Cb,
    unsigned short* __restrict__ Cb2, const unsigned short* __restrict__ v1b,
    int N, int K) {
  constexpr int NMB = BT / BM;       // m-blocks
  constexpr int PA = BM / 32;        // A staging chunks
  constexpr int PB = BN / 32;        // B staging chunks
  constexpr int MI = BM / 32;        // per-wave m frags
  constexpr int NI = BN / 32;        // per-wave n frags
  __shared__ unsigned short As[BM * 64];
  __shared__ unsigned short Bs[BN * 64];
  const int tid = threadIdx.x;
  const int lane = tid & 63;
  const int wv = tid >> 6;
  const int wr = wv >> 1, wc = wv & 1;
  const int nwg = gridDim.x;
  const int bid = blockIdx.x;
  const int swz = (bid & 7) * (nwg >> 3) + (bid >> 3);   // bijective: nwg%8==0
  const int m0 = (swz % NMB) * BM;
  const int n0 = (swz / NMB) * BN;
  const int l15 = lane & 15, g = lane >> 4;
  const int trow = tid >> 3;         // 0..31
  const int tcb = (tid & 7) << 4;    // byte col 0..112 step 16

  const unsigned short* xrow[PA];
  const unsigned short* wrow[PB];
  int aoff[PA], boff[PB];
#pragma unroll
  for (int p = 0; p < PA; ++p) {
    int r = p * 32 + trow;
    xrow[p] = X + (size_t)(m0 + r) * K + (tcb >> 1);
    aoff[p] = r * 128 + (tcb ^ ((trow & 7) << 4));   // T2 XOR swizzle
  }
#pragma unroll
  for (int p = 0; p < PB; ++p) {
    int r = p * 32 + trow;
    int rn = n0 + r; if (rn > N - 1) rn = N - 1;     // clamp OOB N rows
    wrow[p] = W + (size_t)rn * K + (tcb >> 1);
    boff[p] = r * 128 + (tcb ^ ((trow & 7) << 4));
  }
  const int rdswz = (l15 & 7) << 4;

  f32x4 acc[MI][NI];
  const f32x4 fz = {0.f, 0.f, 0.f, 0.f};
#pragma unroll
  for (int i = 0; i < MI; ++i)
#pragma unroll
    for (int j = 0; j < NI; ++j) acc[i][j] = fz;

  u16x8 stg[PA + PB];
#pragma unroll
  for (int p = 0; p < PA; ++p) stg[p] = *reinterpret_cast<const u16x8*>(xrow[p]);
#pragma unroll
  for (int p = 0; p < PB; ++p) stg[PA + p] = *reinterpret_cast<const u16x8*>(wrow[p]);

  for (int k0 = 0; k0 < K; k0 += 64) {
    __syncthreads();
#pragma unroll
    for (int p = 0; p < PA; ++p)
      *reinterpret_cast<u16x8*>(reinterpret_cast<char*>(As) + aoff[p]) = stg[p];
#pragma unroll
    for (int p = 0; p < PB; ++p)
      *reinterpret_cast<u16x8*>(reinterpret_cast<char*>(Bs) + boff[p]) = stg[PA + p];
    __syncthreads();
    if (k0 + 64 < K) {
#pragma unroll
      for (int p = 0; p < PA; ++p)
        stg[p] = *reinterpret_cast<const u16x8*>(xrow[p] + k0 + 64);
#pragma unroll
      for (int p = 0; p < PB; ++p)
        stg[PA + p] = *reinterpret_cast<const u16x8*>(wrow[p] + k0 + 64);
    }
#pragma unroll
    for (int kk = 0; kk < 2; ++kk) {
      const int kbyte = kk * 64 + g * 16;
      bf16x8 a[MI], bb[NI];
#pragma unroll
      for (int mi = 0; mi < MI; ++mi) {
        int ar = wr * (BM / 2) + mi * 16 + l15;
        a[mi] = *reinterpret_cast<const bf16x8*>(
            reinterpret_cast<const char*>(As) + ar * 128 + (kbyte ^ rdswz));
      }
#pragma unroll
      for (int ni = 0; ni < NI; ++ni) {
        int br = wc * (BN / 2) + ni * 16 + l15;
        bb[ni] = *reinterpret_cast<const bf16x8*>(
            reinterpret_cast<const char*>(Bs) + br * 128 + (kbyte ^ rdswz));
      }
#pragma unroll
      for (int mi = 0; mi < MI; ++mi)
#pragma unroll
        for (int ni = 0; ni < NI; ++ni)
          acc[mi][ni] = __builtin_amdgcn_mfma_f32_16x16x32_bf16(a[mi], bb[ni], acc[mi][ni], 0, 0, 0);
    }
  }
#pragma unroll
  for (int mi = 0; mi < MI; ++mi) {
#pragma unroll
    for (int ni = 0; ni < NI; ++ni) {
      int gn = n0 + wc * (BN / 2) + ni * 16 + l15;
      int gm = m0 + wr * (BM / 2) + mi * 16 + g * 4;
#pragma unroll
      for (int r = 0; r < 4; ++r) {
        float v = acc[mi][ni][r];
        size_t row = (size_t)(gm + r);
        if (EPI == 5) {
          float partner = __shfl_xor(v, 1, 64);
          if ((l15 & 1) == 0 && gn < N)
            Cb[row * (N / 2) + (gn >> 1)] = f2bf(gelu_tanh(v) * partner);
        } else if (gn < N) {
          if (EPI == 0) Cf[row * N + gn] = v;
          else if (EPI == 1) Cf[row * N + gn] += v;
          else if (EPI == 2) Cf[row * N + gn] = 30.f * tanhf(v * (1.f / 30.f));
          else if (EPI == 3) Cb[row * N + gn] = f2bf(v);
          else if (EPI == 4) {
            if (gn < C2) Cb[row * C2 + gn] = f2bf(v);                       // q,k
            else Cb2[row * CC + (gn - C2)] = f2bf(0.5f * v + 0.5f * bf2f(v1b[row * CC + (gn - C2)]));
          }
        }
      }
    }
  }
}

// ---------------- flash attention (causal; ALiBi dead on causal region) ----------------
// Double-buffered K/V staging; LPT dispatch order (qb descending).
__global__ __launch_bounds__(256) void attn_kernel(
    const unsigned short* __restrict__ qkb, const unsigned short* __restrict__ vmix,
    unsigned short* __restrict__ ybf) {
  __shared__ unsigned short Kl[2][64 * 56];   // K tile, row pad 56
  __shared__ unsigned short Vt[2][48 * 72];   // V tile transposed [d][key], row pad 72
  __shared__ unsigned short Pl[4][16 * 72];   // per-wave P buffer [q][key]
  const int bid = blockIdx.x;                 // 384 = 16*24
  const int qb = 15 - (bid / 24);             // heavy blocks dispatched first (LPT)
  const int bh = bid % 24;
  const int b = bh / NH, h = bh % NH;
  const int tid = threadIdx.x, lane = tid & 63, wv = tid >> 6;
  const int l15 = lane & 15, g = lane >> 4;
  const int rb = b * TT;
  const int q0 = qb * 64 + wv * 16;
  const float scale = 0.14433756729740643f;   // 1/sqrt(48)

  auto stage = [&](int kb, int buf) {
    const int r0 = rb + kb * 64;
#pragma unroll
    for (int jj = 0; jj < 3; ++jj) {
      int fi = tid + 256 * jj;                // 0..767
      int r = fi / 12, dq = (fi % 12) * 4;
      *reinterpret_cast<ushort4*>(&Kl[buf][r * 56 + dq]) =
          *reinterpret_cast<const ushort4*>(qkb + (size_t)(r0 + r) * C2 + CC + h * HD + dq);
    }
#pragma unroll
    for (int jj = 0; jj < 3; ++jj) {
      int e4 = tid + 256 * jj;                // 0..767 -> 4 d each
      int r = e4 / 12, d4 = (e4 % 12) * 4;
      ushort4 v = *reinterpret_cast<const ushort4*>(vmix + (size_t)(r0 + r) * CC + h * HD + d4);
      Vt[buf][(d4 + 0) * 72 + r] = v.x;
      Vt[buf][(d4 + 1) * 72 + r] = v.y;
      Vt[buf][(d4 + 2) * 72 + r] = v.z;
      Vt[buf][(d4 + 3) * 72 + r] = v.w;
    }
  };

  // Q fragments, K-dim padded 48->64 with zeros
  bf16x8 qa[2];
  {
    const unsigned short* qp = qkb + (size_t)(rb + q0 + l15) * C2 + h * HD;
    qa[0] = *reinterpret_cast<const bf16x8*>(qp + 8 * g);
    if (g < 2) qa[1] = *reinterpret_cast<const bf16x8*>(qp + 32 + 8 * g);
    else { u16x8 z = {0,0,0,0,0,0,0,0}; qa[1] = __builtin_bit_cast(bf16x8, z); }
  }

  float mrow[4], lrow[4];
  f32x4 o[3];
  const f32x4 fz = {0.f, 0.f, 0.f, 0.f};
#pragma unroll
  for (int r = 0; r < 4; ++r) { mrow[r] = -1e30f; lrow[r] = 0.f; }
  o[0] = fz; o[1] = fz; o[2] = fz;

  stage(0, 0);
  __syncthreads();

  for (int kb = 0; kb <= qb; ++kb) {
    const int cur = kb & 1;
    // prefetch next tile into the other buffer (loads issue early, writes land
    // when data returns; no barrier needed — other waves read only buf `cur`)
    if (kb < qb) stage(kb + 1, cur ^ 1);

    f32x4 s[4];
    s[0] = fz; s[1] = fz; s[2] = fz; s[3] = fz;
#pragma unroll
    for (int c = 0; c < 2; ++c) {
#pragma unroll
      for (int t4 = 0; t4 < 4; ++t4) {
        bf16x8 kf;
        if (c == 1 && g >= 2) {
          u16x8 z = {0,0,0,0,0,0,0,0};
          kf = __builtin_bit_cast(bf16x8, z);
        } else {
          kf = *reinterpret_cast<const bf16x8*>(&Kl[cur][(t4 * 16 + l15) * 56 + c * 32 + 8 * g]);
        }
        s[t4] = __builtin_amdgcn_mfma_f32_16x16x32_bf16(qa[c], kf, s[t4], 0, 0, 0);
      }
    }
#pragma unroll
    for (int t4 = 0; t4 < 4; ++t4) s[t4] *= scale;
    if (kb == qb) {
#pragma unroll
      for (int t4 = 0; t4 < 4; ++t4) {
        int key = kb * 64 + t4 * 16 + l15;
#pragma unroll
        for (int r = 0; r < 4; ++r)
          if (key > q0 + g * 4 + r) s[t4][r] = -1e30f;
      }
    }
    float pv[4][4];
#pragma unroll
    for (int r = 0; r < 4; ++r) {
      float tm = fmaxf(fmaxf(s[0][r], s[1][r]), fmaxf(s[2][r], s[3][r]));
#pragma unroll
      for (int mm = 1; mm < 16; mm <<= 1) tm = fmaxf(tm, __shfl_xor(tm, mm, 64));
      float mnew = fmaxf(mrow[r], tm);
      float cf = __expf(mrow[r] - mnew);
      lrow[r] *= cf;
      o[0][r] *= cf; o[1][r] *= cf; o[2][r] *= cf;
      mrow[r] = mnew;
      float rs = 0.f;
#pragma unroll
      for (int t4 = 0; t4 < 4; ++t4) {
        float pe = __expf(s[t4][r] - mnew);
        pv[t4][r] = pe; rs += pe;
      }
#pragma unroll
      for (int mm = 1; mm < 16; mm <<= 1) rs += __shfl_xor(rs, mm, 64);
      lrow[r] += rs;
    }
#pragma unroll
    for (int t4 = 0; t4 < 4; ++t4)
#pragma unroll
      for (int r = 0; r < 4; ++r)
        Pl[wv][(g * 4 + r) * 72 + t4 * 16 + l15] = f2bf(pv[t4][r]);
#pragma unroll
    for (int c = 0; c < 2; ++c) {
      bf16x8 pa = *reinterpret_cast<const bf16x8*>(&Pl[wv][l15 * 72 + c * 32 + 8 * g]);
#pragma unroll
      for (int dt = 0; dt < 3; ++dt) {
        bf16x8 vb = *reinterpret_cast<const bf16x8*>(&Vt[cur][(dt * 16 + l15) * 72 + c * 32 + 8 * g]);
        o[dt] = __builtin_amdgcn_mfma_f32_16x16x32_bf16(pa, vb, o[dt], 0, 0, 0);
      }
    }
    __syncthreads();   // next buffer fully staged; everyone done reading cur
  }
#pragma unroll
  for (int r = 0; r < 4; ++r) {
    float inv = 1.f / lrow[r];
    int tr = q0 + g * 4 + r;
#pragma unroll
    for (int dt = 0; dt < 3; ++dt)
      ybf[(size_t)(rb + tr) * CC + h * HD + dt * 16 + l15] = f2bf(o[dt][r] * inv);
  }
}

// ---------------- launcher ----------------
extern "C" void kernel_launch(void* const* d_in, const int* in_sizes, int n_in,
                              void* d_out, int out_size, void* d_ws, size_t ws_size,
                              hipStream_t stream) {
  (void)in_sizes; (void)n_in; (void)out_size; (void)ws_size;
  const int*   idx  = (const int*)d_in[0];
  const float* wte  = (const float*)d_in[1];
  const float* Wqkv = (const float*)d_in[2];
  const float* Wo   = (const float*)d_in[3];
  const float* ln1w = (const float*)d_in[4];
  const float* ln1b = (const float*)d_in[5];
  const float* ln2w = (const float*)d_in[6];
  const float* ln2b = (const float*)d_in[7];
  const float* lam  = (const float*)d_in[8];
  const float* Wg   = (const float*)d_in[9];
  const float* Wu   = (const float*)d_in[10];
  const float* Wd   = (const float*)d_in[11];
  const float* lnfw = (const float*)d_in[12];
  const float* lnfb = (const float*)d_in[13];
  float* out = (float*)d_out;

  char* ws = (char*)d_ws;
  size_t off = 0;
  auto alloc = [&](size_t bytes) -> void* {
    void* p = ws + off;
    off = (off + bytes + 255) & ~(size_t)255;
    return p;
  };
  unsigned short* wqkv_b = (unsigned short*)alloc((size_t)NL * C3 * CC * 2);
  unsigned short* wo_b   = (unsigned short*)alloc((size_t)NL * CC * CC * 2);
  unsigned short* wgu_b  = (unsigned short*)alloc((size_t)NL * 2 * C2 * CC * 2);
  unsigned short* wd_b   = (unsigned short*)alloc((size_t)NL * CC * C2 * 2);
  unsigned short* wte_b  = (unsigned short*)alloc((size_t)VV * CC * 2);
  float* x   = (float*)alloc((size_t)BT * CC * 4);
  float* x0  = (float*)alloc((size_t)BT * CC * 4);
  unsigned short* hb    = (unsigned short*)alloc((size_t)BT * CC * 2);
  unsigned short* qkb   = (unsigned short*)alloc((size_t)BT * C2 * 2);
  unsigned short* v1b   = (unsigned short*)alloc((size_t)BT * CC * 2);
  unsigned short* vmixb = (unsigned short*)alloc((size_t)BT * CC * 2);
  unsigned short* yb    = (unsigned short*)alloc((size_t)BT * CC * 2);
  unsigned short* gub   = (unsigned short*)alloc((size_t)BT * C2 * 2);

  auto cvt = [&](const float* in, unsigned short* o, size_t n) {
    cvt_kernel<<<dim3(2048), 256, 0, stream>>>(in, o, (int)(n / 4));
  };
  cvt(Wqkv, wqkv_b, (size_t)NL * C3 * CC);
  cvt(Wo,   wo_b,   (size_t)NL * CC * CC);
  cvt(Wd,   wd_b,   (size_t)NL * CC * C2);
  cvt(wte,  wte_b,  (size_t)VV * CC);
  cvt_gu_kernel<<<dim3(2048), 256, 0, stream>>>(Wg, Wu, wgu_b, NL * C2 * (CC / 4));

  embed_kernel<<<dim3(BT), 256, 0, stream>>>(idx, wte, x, x0, hb);

  auto nb = [](int N, int BN) { return (N + BN - 1) / BN; };
  // v1 = raw-embed @ W_qkv[0] v-chunk^T  -> bf16   (32 m-blocks x 9 n-blocks)
  gemm_bt<3, 64, 64><<<dim3(32 * nb(CC, 64)), 256, 0, stream>>>(
      hb, wqkv_b + (size_t)C2 * CC, nullptr, v1b, nullptr, nullptr, CC, CC);

  for (int l = 0; l < NL; ++l) {
    ln_kernel<1><<<dim3(512), 256, 0, stream>>>(x, x0, lam + 2 * l, ln1w + l * CC, ln1b + l * CC, x, hb);
    gemm_bt<4, 64, 128><<<dim3(32 * nb(C3, 128)), 256, 0, stream>>>(
        hb, wqkv_b + (size_t)l * C3 * CC, nullptr, qkb, vmixb, v1b, C3, CC);
    attn_kernel<<<dim3(16 * 24), 256, 0, stream>>>(qkb, vmixb, yb);
    gemm_bt<1, 64, 64><<<dim3(32 * nb(CC, 64)), 256, 0, stream>>>(
        yb, wo_b + (size_t)l * CC * CC, x, nullptr, nullptr, nullptr, CC, CC);
    ln_kernel<0><<<dim3(512), 256, 0, stream>>>(x, nullptr, nullptr, ln2w + l * CC, ln2b + l * CC, nullptr, hb);
    gemm_bt<5, 64, 128><<<dim3(32 * nb(2 * C2, 128)), 256, 0, stream>>>(
        hb, wgu_b + (size_t)l * 2 * C2 * CC, nullptr, gub, nullptr, nullptr, 2 * C2, CC);
    gemm_bt<1, 64, 64><<<dim3(32 * nb(CC, 64)), 256, 0, stream>>>(
        gub, wd_b + (size_t)l * CC * C2, x, nullptr, nullptr, nullptr, CC, C2);
  }

  ln_kernel<0><<<dim3(512), 256, 0, stream>>>(x, nullptr, nullptr, lnfw, lnfb, nullptr, hb);
  gemm_bt<2, 128, 128><<<dim3(16 * nb(VV, 128)), 256, 0, stream>>>(
      hb, wte_b, out, nullptr, nullptr, nullptr, VV, CC);
}